// Round 13
// baseline (233.682 us; speedup 1.0000x reference)
//
#include <hip/hip_runtime.h>
#include <hip/hip_bf16.h>
#include <cstddef>

#define NN 8192
#define FF 128
#define EPSF 1e-8f
#define KSPLIT 8   // grid-level split-K for spmm

typedef __attribute__((ext_vector_type(8))) short short8_t;
typedef __attribute__((ext_vector_type(4))) float f32x4_t;

static __device__ __forceinline__ unsigned short f2bf(float f) {
    unsigned u = __builtin_bit_cast(unsigned, f);
    u = (u + 0x7FFFu + ((u >> 16) & 1u)) >> 16;   // round-to-nearest-even
    return (unsigned short)u;
}
static __device__ __forceinline__ float bf2f(unsigned short h) {
    return __builtin_bit_cast(float, ((unsigned)h) << 16);
}

// System-scope non-temporal 16B load: bypasses L2/L3 allocation AND the
// L3 hit path (R13 theory: ~50% L3-hits at ~2-2.5 TB/s service rate are
// what pin streaming kernels at 3.3-4.3 TB/s app-level).
static __device__ __forceinline__ f32x4_t ld_bypass(const float* p) {
    f32x4_t v;
    asm volatile("global_load_dwordx4 %0, %1, off sc0 sc1 nt"
                 : "=v"(v) : "v"(p));
    return v;
}

// Fragment-native layouts (1 KB block = one 16-row x 32-k MFMA fragment;
// lane(m,b)'s 16B chunk at ((m*4+b)*16) bytes -> wave fragment load covers
// a contiguous 1KB span).
static __device__ __forceinline__ size_t lb2_idx(int row, int k) {
    return ((size_t)(row >> 4) * 256 + (k >> 5)) * 512
         + ((row & 15) * 4 + ((k >> 3) & 3)) * 8 + (k & 7);
}
static __device__ __forceinline__ size_t ss2_idx(int n, int k) {
    return ((size_t)(k >> 5) * 8 + (n >> 4)) * 512
         + ((n & 15) * 4 + ((k >> 3) & 3)) * 8 + (k & 7);
}

// ---------------------------------------------------------------------------
// Pass A1: L = adj + learn (eps*noise <= 1e-8: below bf16 ulp of L, ~5e-9
// relative on degree -> noise never read; proven R3).
// R13: the 8 input loads use sc0+sc1+nt (system scope, no cache allocation)
// via inline asm; explicit vmcnt(0) + sched_barrier(0) before consumers
// (rule #18: compiler hoists register-only consumers past asm waitcnt).
// ---------------------------------------------------------------------------
__global__ __launch_bounds__(256) void fuse_combine_kernel(
    const float* __restrict__ adj, const float* __restrict__ learn,
    unsigned short* __restrict__ Lb, float* __restrict__ degree)
{
    const int row = blockIdx.x >> 1;
    const int e0 = (blockIdx.x & 1) * 4096 + threadIdx.x * 8;   // k of chunk 0
    const size_t base = (size_t)row * NN + e0;
    // ---- 8 bypass loads issued back-to-back ----
    const f32x4_t a0 = ld_bypass(adj + base);
    const f32x4_t a1 = ld_bypass(adj + base + 4);
    const f32x4_t a2 = ld_bypass(adj + base + 2048);
    const f32x4_t a3 = ld_bypass(adj + base + 2052);
    const f32x4_t l0 = ld_bypass(learn + base);
    const f32x4_t l1 = ld_bypass(learn + base + 4);
    const f32x4_t l2 = ld_bypass(learn + base + 2048);
    const f32x4_t l3 = ld_bypass(learn + base + 2052);
    asm volatile("s_waitcnt vmcnt(0)" ::: "memory");
    __builtin_amdgcn_sched_barrier(0);
    // ---- consumers ----
    const f32x4_t v0 = a0 + l0, v1 = a1 + l1, v2 = a2 + l2, v3 = a3 + l3;
    short8_t p0, p1;
    p0[0] = (short)f2bf(v0.x); p0[1] = (short)f2bf(v0.y);
    p0[2] = (short)f2bf(v0.z); p0[3] = (short)f2bf(v0.w);
    p0[4] = (short)f2bf(v1.x); p0[5] = (short)f2bf(v1.y);
    p0[6] = (short)f2bf(v1.z); p0[7] = (short)f2bf(v1.w);
    p1[0] = (short)f2bf(v2.x); p1[1] = (short)f2bf(v2.y);
    p1[2] = (short)f2bf(v2.z); p1[3] = (short)f2bf(v2.w);
    p1[4] = (short)f2bf(v3.x); p1[5] = (short)f2bf(v3.y);
    p1[6] = (short)f2bf(v3.z); p1[7] = (short)f2bf(v3.w);
    *(short8_t*)(Lb + lb2_idx(row, e0)) = p0;           // normal store: Lb -> L3
    *(short8_t*)(Lb + lb2_idx(row, e0 + 2048)) = p1;

    float acc = (v0.x + v0.y) + (v0.z + v0.w) + (v1.x + v1.y) + (v1.z + v1.w)
              + (v2.x + v2.y) + (v2.z + v2.w) + (v3.x + v3.y) + (v3.z + v3.w);
#pragma unroll
    for (int o = 32; o; o >>= 1) acc += __shfl_down(acc, o);
    __shared__ float red[4];
    if ((threadIdx.x & 63) == 0) red[threadIdx.x >> 6] = acc;
    __syncthreads();
    if (threadIdx.x == 0)
        atomicAdd(degree + row, red[0] + red[1] + red[2] + red[3]);
}

// s[i] = rsqrt(degree[i] + 1 (self loop) + eps)
__global__ __launch_bounds__(256) void s_kernel(
    const float* __restrict__ degree, float* __restrict__ s)
{
    const int i = blockIdx.x * 256 + threadIdx.x;
    s[i] = rsqrtf(degree[i] + 1.0f + EPSF);
}

// ---------------------------------------------------------------------------
// Pass B: ss2(n=c, k=j) = s[j] * (x @ W)[j][c]  (bf16, 2 MB, fragment-native)
// ---------------------------------------------------------------------------
__global__ __launch_bounds__(256) void support_kernel(
    const float* __restrict__ x, const float* __restrict__ w,
    const float* __restrict__ s, unsigned short* __restrict__ ss2)
{
    __shared__ float Ws[128 * 128];    // 64 KB
    __shared__ float Xs[32][128];      // 16 KB
    for (int i = threadIdx.x; i < 128 * 128 / 4; i += 256)
        ((float4*)Ws)[i] = ((const float4*)w)[i];
    const int rbase = blockIdx.x * 32;
    for (int i = threadIdx.x; i < 32 * 128 / 4; i += 256)
        ((float4*)&Xs[0][0])[i] = ((const float4*)(x + (size_t)rbase * 128))[i];
    __syncthreads();

    const int c = threadIdx.x & 127;
    const int h = threadIdx.x >> 7;
    for (int r = h; r < 32; r += 2) {
        float acc = 0.f;
#pragma unroll 8
        for (int k = 0; k < 128; ++k) acc += Xs[r][k] * Ws[k * 128 + c];
        const int grow = rbase + r;
        ss2[ss2_idx(c, grow)] = f2bf(acc * s[grow]);
    }
}

// ---------------------------------------------------------------------------
// Pass C (R10 exact, proven ~52us): out[i][n] =
//   s[i] * ( sum_j L[i][j]*SS[j][n] + SS[i][n] )
// All 10 fragment loads batched BEFORE the 16-MFMA cluster.
// ---------------------------------------------------------------------------
template<bool ATOMIC>
__global__ __launch_bounds__(256) void spmm_bf16_kernel(
    const unsigned short* __restrict__ Lb,
    const unsigned short* __restrict__ ss2,
    const float* __restrict__ s, float* __restrict__ outp)
{
    const int ks   = blockIdx.y;            // 0..KSPLIT-1
    const int i0   = blockIdx.x * 128;      // M-block base
    const int wave = threadIdx.x >> 6;      // 0..3
    const int lane = threadIdx.x & 63;
    const int m = lane & 15;                // A-row / B-col within fragment
    const int b = lane >> 4;                // k-subgroup (8 elems each)
    const int laneoff = (m * 4 + b) * 8;    // elems within 1KB fragment block
    const int rb0 = (i0 >> 4) + wave * 2;   // 16-row block index of f=0
    const int kb0 = ks * (256 / KSPLIT);    // 32 kb-blocks per ks

    f32x4_t acc[2][8];
#pragma unroll
    for (int f = 0; f < 2; ++f)
#pragma unroll
        for (int t = 0; t < 8; ++t) acc[f][t] = (f32x4_t){0.f, 0.f, 0.f, 0.f};

    const unsigned short* a0p = Lb + (size_t)(rb0 + 0) * 256 * 512 + laneoff;
    const unsigned short* a1p = Lb + (size_t)(rb0 + 1) * 256 * 512 + laneoff;
    const unsigned short* bp  = ss2 + laneoff;

    for (int kb = kb0; kb < kb0 + 256 / KSPLIT; ++kb) {
        const unsigned short* bkb = bp + (size_t)kb * 4096;
        // ---- batched loads: 8 B-frags + 2 A-frags, no MFMA in between ----
        const short8_t b0 = *(const short8_t*)(bkb + 0 * 512);
        const short8_t b1 = *(const short8_t*)(bkb + 1 * 512);
        const short8_t b2 = *(const short8_t*)(bkb + 2 * 512);
        const short8_t b3 = *(const short8_t*)(bkb + 3 * 512);
        const short8_t b4 = *(const short8_t*)(bkb + 4 * 512);
        const short8_t b5 = *(const short8_t*)(bkb + 5 * 512);
        const short8_t b6 = *(const short8_t*)(bkb + 6 * 512);
        const short8_t b7 = *(const short8_t*)(bkb + 7 * 512);
        const short8_t af0 = *(const short8_t*)(a0p + (size_t)kb * 512);
        const short8_t af1 = *(const short8_t*)(a1p + (size_t)kb * 512);
        // ---- MFMA cluster ----
        acc[0][0] = __builtin_amdgcn_mfma_f32_16x16x32_bf16(af0, b0, acc[0][0], 0, 0, 0);
        acc[1][0] = __builtin_amdgcn_mfma_f32_16x16x32_bf16(af1, b0, acc[1][0], 0, 0, 0);
        acc[0][1] = __builtin_amdgcn_mfma_f32_16x16x32_bf16(af0, b1, acc[0][1], 0, 0, 0);
        acc[1][1] = __builtin_amdgcn_mfma_f32_16x16x32_bf16(af1, b1, acc[1][1], 0, 0, 0);
        acc[0][2] = __builtin_amdgcn_mfma_f32_16x16x32_bf16(af0, b2, acc[0][2], 0, 0, 0);
        acc[1][2] = __builtin_amdgcn_mfma_f32_16x16x32_bf16(af1, b2, acc[1][2], 0, 0, 0);
        acc[0][3] = __builtin_amdgcn_mfma_f32_16x16x32_bf16(af0, b3, acc[0][3], 0, 0, 0);
        acc[1][3] = __builtin_amdgcn_mfma_f32_16x16x32_bf16(af1, b3, acc[1][3], 0, 0, 0);
        acc[0][4] = __builtin_amdgcn_mfma_f32_16x16x32_bf16(af0, b4, acc[0][4], 0, 0, 0);
        acc[1][4] = __builtin_amdgcn_mfma_f32_16x16x32_bf16(af1, b4, acc[1][4], 0, 0, 0);
        acc[0][5] = __builtin_amdgcn_mfma_f32_16x16x32_bf16(af0, b5, acc[0][5], 0, 0, 0);
        acc[1][5] = __builtin_amdgcn_mfma_f32_16x16x32_bf16(af1, b5, acc[1][5], 0, 0, 0);
        acc[0][6] = __builtin_amdgcn_mfma_f32_16x16x32_bf16(af0, b6, acc[0][6], 0, 0, 0);
        acc[1][6] = __builtin_amdgcn_mfma_f32_16x16x32_bf16(af1, b6, acc[1][6], 0, 0, 0);
        acc[0][7] = __builtin_amdgcn_mfma_f32_16x16x32_bf16(af0, b7, acc[0][7], 0, 0, 0);
        acc[1][7] = __builtin_amdgcn_mfma_f32_16x16x32_bf16(af1, b7, acc[1][7], 0, 0, 0);
    }

    // C/D layout: col = lane&15, row = (lane>>4)*4 + reg  [measured m89/m91]
#pragma unroll
    for (int f = 0; f < 2; ++f) {
#pragma unroll
        for (int nt = 0; nt < 8; ++nt) {
            const int n = nt * 16 + m;
#pragma unroll
            for (int r = 0; r < 4; ++r) {
                const int ro = i0 + wave * 32 + f * 16 + 4 * b + r;
                float v = acc[f][nt][r];
                if (ATOMIC) {
                    if (ks == 0) v += bf2f(ss2[ss2_idx(n, ro)]);
                    atomicAdd(outp + (size_t)ro * FF + n, s[ro] * v);
                } else {
                    outp[(size_t)ks * NN * FF + (size_t)ro * FF + n] = v;
                }
            }
        }
    }
}

// Reduce KSPLIT partials + identity term + row scaling -> out (f32).
__global__ __launch_bounds__(256) void reduce_kernel(
    const float* __restrict__ part, const unsigned short* __restrict__ ss2,
    const float* __restrict__ s, float* __restrict__ out)
{
    const int idx4 = blockIdx.x * 256 + threadIdx.x;  // 0 .. NN*FF/4-1
    const int idx = idx4 * 4;
    const int gi = idx >> 7;          // row i
    const int cc = idx & 127;         // col n base (cc..cc+3 same gi)
    f32x4_t v = (f32x4_t){0.f, 0.f, 0.f, 0.f};
#pragma unroll
    for (int k = 0; k < KSPLIT; ++k)
        v += *(const f32x4_t*)(part + (size_t)k * NN * FF + idx);
    const float si = s[gi];
    float4 o;
    o.x = si * (v.x + bf2f(ss2[ss2_idx(cc + 0, gi)]));
    o.y = si * (v.y + bf2f(ss2[ss2_idx(cc + 1, gi)]));
    o.z = si * (v.z + bf2f(ss2[ss2_idx(cc + 2, gi)]));
    o.w = si * (v.w + bf2f(ss2[ss2_idx(cc + 3, gi)]));
    *(float4*)(out + idx) = o;
}

extern "C" void kernel_launch(void* const* d_in, const int* in_sizes, int n_in,
                              void* d_out, int out_size, void* d_ws, size_t ws_size,
                              hipStream_t stream) {
    const float* x     = (const float*)d_in[0];
    const float* adj   = (const float*)d_in[1];
    const float* w     = (const float*)d_in[3];
    const float* learn = (const float*)d_in[4];
    float* out = (float*)d_out;

    // ws layout: degree | s | ss2 | Lb | (part)
    float* degree = (float*)d_ws;
    float* s      = degree + NN;
    unsigned short* ss2 = (unsigned short*)(s + NN);
    unsigned short* Lb  = ss2 + (size_t)FF * NN;
    float* part         = (float*)(Lb + (size_t)NN * NN);

    const size_t need_base = 2 * NN * 4 + (size_t)FF * NN * 2
                           + (size_t)NN * NN * 2;
    const size_t need_part = need_base + (size_t)KSPLIT * NN * FF * 4; // ~162 MB

    hipMemsetAsync(degree, 0, NN * sizeof(float), stream);
    fuse_combine_kernel<<<NN * 2, 256, 0, stream>>>(adj, learn, Lb, degree);
    s_kernel<<<NN / 256, 256, 0, stream>>>(degree, s);
    support_kernel<<<NN / 32, 256, 0, stream>>>(x, w, s, ss2);

    if (ws_size >= need_part) {
        spmm_bf16_kernel<false><<<dim3(NN / 128, KSPLIT), 256, 0, stream>>>(
            Lb, ss2, s, part);
        reduce_kernel<<<NN * FF / 4 / 256, 256, 0, stream>>>(part, ss2, s, out);
    } else {
        hipMemsetAsync(d_out, 0, (size_t)NN * FF * sizeof(float), stream);
        spmm_bf16_kernel<true><<<dim3(NN / 128, KSPLIT), 256, 0, stream>>>(
            Lb, ss2, s, out);
    }
}

// Round 14
// 225.818 us; speedup vs baseline: 1.0348x; 1.0348x over previous
//
#include <hip/hip_runtime.h>
#include <hip/hip_bf16.h>
#include <cstddef>

#define NN 8192
#define FF 128
#define EPSF 1e-8f
#define KSPLIT 8   // grid-level split-K for spmm

typedef __attribute__((ext_vector_type(8))) short short8_t;
typedef __attribute__((ext_vector_type(4))) float f32x4_t;

static __device__ __forceinline__ unsigned short f2bf(float f) {
    unsigned u = __builtin_bit_cast(unsigned, f);
    u = (u + 0x7FFFu + ((u >> 16) & 1u)) >> 16;   // round-to-nearest-even
    return (unsigned short)u;
}
static __device__ __forceinline__ float bf2f(unsigned short h) {
    return __builtin_bit_cast(float, ((unsigned)h) << 16);
}
static __device__ __forceinline__ f32x4_t ntl(const float* p) {
    return __builtin_nontemporal_load((const f32x4_t*)p);
}
// s(degree): single shared definition -> bit-identical in all consumers.
static __device__ __forceinline__ float deg2s(float d) {
    return rsqrtf(d + 1.0f + EPSF);   // +1 = self loop
}

// Fragment-native layouts (1 KB block = one 16-row x 32-k MFMA fragment;
// lane(m,b)'s 16B chunk at ((m*4+b)*16) bytes -> wave fragment load covers
// a contiguous 1KB span).
static __device__ __forceinline__ size_t lb2_idx(int row, int k) {
    return ((size_t)(row >> 4) * 256 + (k >> 5)) * 512
         + ((row & 15) * 4 + ((k >> 3) & 3)) * 8 + (k & 7);
}
static __device__ __forceinline__ size_t ss2_idx(int n, int k) {
    return ((size_t)(k >> 5) * 8 + (n >> 4)) * 512
         + ((n & 15) * 4 + ((k >> 3) & 3)) * 8 + (k & 7);
}

// ---------------------------------------------------------------------------
// Pass A: L = adj + learn (eps*noise <= 1e-8: below bf16 ulp of L, ~5e-9
// relative on degree -> noise never read; proven R3). One-shot per thread,
// NT loads on single-use inputs, batched-issue + sched_barrier(0) (R12 best).
// Steady-state limiter [R11-R13 measured]: ~46% of the 512 MB input re-read
// sits in the memory-side Infinity Cache whose hit path services ~1.7-2 TB/s
// and is NOT bypassable (sc0/sc1/nt ineffective on reads) -> ~155 us floor.
// ---------------------------------------------------------------------------
__global__ __launch_bounds__(256) void fuse_combine_kernel(
    const float* __restrict__ adj, const float* __restrict__ learn,
    unsigned short* __restrict__ Lb, float* __restrict__ degree)
{
    const int row = blockIdx.x >> 1;
    const int e0 = (blockIdx.x & 1) * 4096 + threadIdx.x * 8;   // k of chunk 0
    const size_t base = (size_t)row * NN + e0;
    const f32x4_t a0 = ntl(adj + base);
    const f32x4_t a1 = ntl(adj + base + 4);
    const f32x4_t a2 = ntl(adj + base + 2048);
    const f32x4_t a3 = ntl(adj + base + 2052);
    const f32x4_t l0 = ntl(learn + base);
    const f32x4_t l1 = ntl(learn + base + 4);
    const f32x4_t l2 = ntl(learn + base + 2048);
    const f32x4_t l3 = ntl(learn + base + 2052);
    __builtin_amdgcn_sched_barrier(0);
    const f32x4_t v0 = a0 + l0, v1 = a1 + l1, v2 = a2 + l2, v3 = a3 + l3;
    short8_t p0, p1;
    p0[0] = (short)f2bf(v0.x); p0[1] = (short)f2bf(v0.y);
    p0[2] = (short)f2bf(v0.z); p0[3] = (short)f2bf(v0.w);
    p0[4] = (short)f2bf(v1.x); p0[5] = (short)f2bf(v1.y);
    p0[6] = (short)f2bf(v1.z); p0[7] = (short)f2bf(v1.w);
    p1[0] = (short)f2bf(v2.x); p1[1] = (short)f2bf(v2.y);
    p1[2] = (short)f2bf(v2.z); p1[3] = (short)f2bf(v2.w);
    p1[4] = (short)f2bf(v3.x); p1[5] = (short)f2bf(v3.y);
    p1[6] = (short)f2bf(v3.z); p1[7] = (short)f2bf(v3.w);
    *(short8_t*)(Lb + lb2_idx(row, e0)) = p0;
    *(short8_t*)(Lb + lb2_idx(row, e0 + 2048)) = p1;

    float acc = (v0.x + v0.y) + (v0.z + v0.w) + (v1.x + v1.y) + (v1.z + v1.w)
              + (v2.x + v2.y) + (v2.z + v2.w) + (v3.x + v3.y) + (v3.z + v3.w);
#pragma unroll
    for (int o = 32; o; o >>= 1) acc += __shfl_down(acc, o);
    __shared__ float red[4];
    if ((threadIdx.x & 63) == 0) red[threadIdx.x >> 6] = acc;
    __syncthreads();
    if (threadIdx.x == 0)
        atomicAdd(degree + row, red[0] + red[1] + red[2] + red[3]);
}

// ---------------------------------------------------------------------------
// Pass B: ss2(n=c, k=j) = s[j] * (x @ W)[j][c]  (bf16, 2 MB, fragment-native)
// R14: s computed inline from degree (s_kernel dispatch eliminated).
// ---------------------------------------------------------------------------
__global__ __launch_bounds__(256) void support_kernel(
    const float* __restrict__ x, const float* __restrict__ w,
    const float* __restrict__ degree, unsigned short* __restrict__ ss2)
{
    __shared__ float Ws[128 * 128];    // 64 KB
    __shared__ float Xs[32][128];      // 16 KB
    for (int i = threadIdx.x; i < 128 * 128 / 4; i += 256)
        ((float4*)Ws)[i] = ((const float4*)w)[i];
    const int rbase = blockIdx.x * 32;
    for (int i = threadIdx.x; i < 32 * 128 / 4; i += 256)
        ((float4*)&Xs[0][0])[i] = ((const float4*)(x + (size_t)rbase * 128))[i];
    __syncthreads();

    const int c = threadIdx.x & 127;
    const int h = threadIdx.x >> 7;
    for (int r = h; r < 32; r += 2) {
        float acc = 0.f;
#pragma unroll 8
        for (int k = 0; k < 128; ++k) acc += Xs[r][k] * Ws[k * 128 + c];
        const int grow = rbase + r;
        ss2[ss2_idx(c, grow)] = f2bf(acc * deg2s(degree[grow]));
    }
}

// ---------------------------------------------------------------------------
// Pass C (R10/R12 exact, proven ~52us): out[i][n] =
//   s[i] * ( sum_j L[i][j]*SS[j][n] + SS[i][n] )
// All 10 fragment loads batched BEFORE the 16-MFMA cluster.
// ---------------------------------------------------------------------------
template<bool ATOMIC>
__global__ __launch_bounds__(256) void spmm_bf16_kernel(
    const unsigned short* __restrict__ Lb,
    const unsigned short* __restrict__ ss2,
    const float* __restrict__ degree, float* __restrict__ outp)
{
    const int ks   = blockIdx.y;            // 0..KSPLIT-1
    const int i0   = blockIdx.x * 128;      // M-block base
    const int wave = threadIdx.x >> 6;      // 0..3
    const int lane = threadIdx.x & 63;
    const int m = lane & 15;                // A-row / B-col within fragment
    const int b = lane >> 4;                // k-subgroup (8 elems each)
    const int laneoff = (m * 4 + b) * 8;    // elems within 1KB fragment block
    const int rb0 = (i0 >> 4) + wave * 2;   // 16-row block index of f=0
    const int kb0 = ks * (256 / KSPLIT);    // 32 kb-blocks per ks

    f32x4_t acc[2][8];
#pragma unroll
    for (int f = 0; f < 2; ++f)
#pragma unroll
        for (int t = 0; t < 8; ++t) acc[f][t] = (f32x4_t){0.f, 0.f, 0.f, 0.f};

    const unsigned short* a0p = Lb + (size_t)(rb0 + 0) * 256 * 512 + laneoff;
    const unsigned short* a1p = Lb + (size_t)(rb0 + 1) * 256 * 512 + laneoff;
    const unsigned short* bp  = ss2 + laneoff;

    for (int kb = kb0; kb < kb0 + 256 / KSPLIT; ++kb) {
        const unsigned short* bkb = bp + (size_t)kb * 4096;
        const short8_t b0 = *(const short8_t*)(bkb + 0 * 512);
        const short8_t b1 = *(const short8_t*)(bkb + 1 * 512);
        const short8_t b2 = *(const short8_t*)(bkb + 2 * 512);
        const short8_t b3 = *(const short8_t*)(bkb + 3 * 512);
        const short8_t b4 = *(const short8_t*)(bkb + 4 * 512);
        const short8_t b5 = *(const short8_t*)(bkb + 5 * 512);
        const short8_t b6 = *(const short8_t*)(bkb + 6 * 512);
        const short8_t b7 = *(const short8_t*)(bkb + 7 * 512);
        const short8_t af0 = *(const short8_t*)(a0p + (size_t)kb * 512);
        const short8_t af1 = *(const short8_t*)(a1p + (size_t)kb * 512);
        acc[0][0] = __builtin_amdgcn_mfma_f32_16x16x32_bf16(af0, b0, acc[0][0], 0, 0, 0);
        acc[1][0] = __builtin_amdgcn_mfma_f32_16x16x32_bf16(af1, b0, acc[1][0], 0, 0, 0);
        acc[0][1] = __builtin_amdgcn_mfma_f32_16x16x32_bf16(af0, b1, acc[0][1], 0, 0, 0);
        acc[1][1] = __builtin_amdgcn_mfma_f32_16x16x32_bf16(af1, b1, acc[1][1], 0, 0, 0);
        acc[0][2] = __builtin_amdgcn_mfma_f32_16x16x32_bf16(af0, b2, acc[0][2], 0, 0, 0);
        acc[1][2] = __builtin_amdgcn_mfma_f32_16x16x32_bf16(af1, b2, acc[1][2], 0, 0, 0);
        acc[0][3] = __builtin_amdgcn_mfma_f32_16x16x32_bf16(af0, b3, acc[0][3], 0, 0, 0);
        acc[1][3] = __builtin_amdgcn_mfma_f32_16x16x32_bf16(af1, b3, acc[1][3], 0, 0, 0);
        acc[0][4] = __builtin_amdgcn_mfma_f32_16x16x32_bf16(af0, b4, acc[0][4], 0, 0, 0);
        acc[1][4] = __builtin_amdgcn_mfma_f32_16x16x32_bf16(af1, b4, acc[1][4], 0, 0, 0);
        acc[0][5] = __builtin_amdgcn_mfma_f32_16x16x32_bf16(af0, b5, acc[0][5], 0, 0, 0);
        acc[1][5] = __builtin_amdgcn_mfma_f32_16x16x32_bf16(af1, b5, acc[1][5], 0, 0, 0);
        acc[0][6] = __builtin_amdgcn_mfma_f32_16x16x32_bf16(af0, b6, acc[0][6], 0, 0, 0);
        acc[1][6] = __builtin_amdgcn_mfma_f32_16x16x32_bf16(af1, b6, acc[1][6], 0, 0, 0);
        acc[0][7] = __builtin_amdgcn_mfma_f32_16x16x32_bf16(af0, b7, acc[0][7], 0, 0, 0);
        acc[1][7] = __builtin_amdgcn_mfma_f32_16x16x32_bf16(af1, b7, acc[1][7], 0, 0, 0);
    }

    // C/D layout: col = lane&15, row = (lane>>4)*4 + reg  [measured m89/m91]
#pragma unroll
    for (int f = 0; f < 2; ++f) {
#pragma unroll
        for (int nt = 0; nt < 8; ++nt) {
            const int n = nt * 16 + m;
#pragma unroll
            for (int r = 0; r < 4; ++r) {
                const int ro = i0 + wave * 32 + f * 16 + 4 * b + r;
                float v = acc[f][nt][r];
                if (ATOMIC) {
                    if (ks == 0) v += bf2f(ss2[ss2_idx(n, ro)]);
                    atomicAdd(outp + (size_t)ro * FF + n, deg2s(degree[ro]) * v);
                } else {
                    outp[(size_t)ks * NN * FF + (size_t)ro * FF + n] = v;
                }
            }
        }
    }
}

// Reduce KSPLIT partials + identity term + row scaling -> out (f32).
__global__ __launch_bounds__(256) void reduce_kernel(
    const float* __restrict__ part, const unsigned short* __restrict__ ss2,
    const float* __restrict__ degree, float* __restrict__ out)
{
    const int idx4 = blockIdx.x * 256 + threadIdx.x;  // 0 .. NN*FF/4-1
    const int idx = idx4 * 4;
    const int gi = idx >> 7;          // row i
    const int cc = idx & 127;         // col n base (cc..cc+3 same gi)
    f32x4_t v = (f32x4_t){0.f, 0.f, 0.f, 0.f};
#pragma unroll
    for (int k = 0; k < KSPLIT; ++k)
        v += *(const f32x4_t*)(part + (size_t)k * NN * FF + idx);
    const float si = deg2s(degree[gi]);
    float4 o;
    o.x = si * (v.x + bf2f(ss2[ss2_idx(cc + 0, gi)]));
    o.y = si * (v.y + bf2f(ss2[ss2_idx(cc + 1, gi)]));
    o.z = si * (v.z + bf2f(ss2[ss2_idx(cc + 2, gi)]));
    o.w = si * (v.w + bf2f(ss2[ss2_idx(cc + 3, gi)]));
    *(float4*)(out + idx) = o;
}

extern "C" void kernel_launch(void* const* d_in, const int* in_sizes, int n_in,
                              void* d_out, int out_size, void* d_ws, size_t ws_size,
                              hipStream_t stream) {
    const float* x     = (const float*)d_in[0];
    const float* adj   = (const float*)d_in[1];
    const float* w     = (const float*)d_in[3];
    const float* learn = (const float*)d_in[4];
    float* out = (float*)d_out;

    // ws layout: degree | ss2 | Lb | (part)
    float* degree = (float*)d_ws;
    unsigned short* ss2 = (unsigned short*)(degree + NN);
    unsigned short* Lb  = ss2 + (size_t)FF * NN;
    float* part         = (float*)(Lb + (size_t)NN * NN);

    const size_t need_base = NN * 4 + (size_t)FF * NN * 2
                           + (size_t)NN * NN * 2;
    const size_t need_part = need_base + (size_t)KSPLIT * NN * FF * 4; // ~162 MB

    hipMemsetAsync(degree, 0, NN * sizeof(float), stream);
    fuse_combine_kernel<<<NN * 2, 256, 0, stream>>>(adj, learn, Lb, degree);
    support_kernel<<<NN / 32, 256, 0, stream>>>(x, w, degree, ss2);

    if (ws_size >= need_part) {
        spmm_bf16_kernel<false><<<dim3(NN / 128, KSPLIT), 256, 0, stream>>>(
            Lb, ss2, degree, part);
        reduce_kernel<<<NN * FF / 4 / 256, 256, 0, stream>>>(part, ss2, degree, out);
    } else {
        hipMemsetAsync(d_out, 0, (size_t)NN * FF * sizeof(float), stream);
        spmm_bf16_kernel<true><<<dim3(NN / 128, KSPLIT), 256, 0, stream>>>(
            Lb, ss2, degree, out);
    }
}